// Round 1
// 970.998 us; speedup vs baseline: 1.0607x; 1.0607x over previous
//
#include <hip/hip_runtime.h>
#include <cstddef>

#define B_      4
#define D_      128
#define H_      512
#define W_      512
#define NCELL_  900     // 30*30 cells per batch
#define NS_     3600    // B_*NCELL_
#define NSP_    3648    // padded to 57*64 for the MFMA tiling
#define NK_     13
#define SC_     3601    // score row length

// _OFFS: pairs (i,j), i*i+j*j<=4, i-major order. OFFS[0]=i (added to x), OFFS[1]=j (added to y)
__constant__ int c_OI[NK_] = {-2,-1,-1,-1, 0, 0,0,0,0, 1,1,1, 2};
__constant__ int c_OJ[NK_] = { 0,-1, 0, 1,-2,-1,0,1,2,-1,0,1, 0};

using short8v = __attribute__((ext_vector_type(8))) short;
using f32x4   = __attribute__((ext_vector_type(4))) float;

__device__ __forceinline__ unsigned short f2bf(float f) {
    unsigned u = __float_as_uint(f);
    return (unsigned short)((u + 0x7FFFu + ((u >> 16) & 1u)) >> 16);   // RNE
}
__device__ __forceinline__ float bf2f(unsigned short h) {
    return __uint_as_float(((unsigned)h) << 16);
}

// ---------------- cell argmax sampling: one wave per cell, shuffle reduce, no LDS -------
// cells 0..3599 -> det1, 3600..7199 -> det2
__global__ __launch_bounds__(256) void sample_kernel(const float* __restrict__ det1,
                                                     const float* __restrict__ det2,
                                                     int* __restrict__ pos_row,
                                                     int* __restrict__ pos_col) {
    int w    = threadIdx.x >> 6;
    int lane = threadIdx.x & 63;
    int cell = blockIdx.x * 4 + w;           // grid = 1800 -> 7200 cells
    const float* det = det1;
    int c = cell;
    if (cell >= NS_) { det = det2; c = cell - NS_; }
    int b  = c / NCELL_;
    int rc = (c % NCELL_) / 30;
    int cc = c % 30;
    int y0 = 16 + rc * 16;
    int x0 = 16 + cc * 16;
    const float* base = det + (b * H_ + y0) * W_ + x0;

    int j  = lane & 15;
    int i0 = lane >> 4;
    float bv = -1e30f; int bt = 0;
#pragma unroll
    for (int q = 0; q < 4; q++) {
        int i  = i0 + 4 * q;                 // flat index t = i*16+j ascends with q
        int tt = i * 16 + j;
        float v = base[i * W_ + j];
        if (v > bv) { bv = v; bt = tt; }     // strict > : first occurrence within lane
    }
#pragma unroll
    for (int s = 32; s > 0; s >>= 1) {
        float ov = __shfl_xor(bv, s, 64);
        int   ot = __shfl_xor(bt, s, 64);
        if (ov > bv || (ov == bv && ot < bt)) { bv = ov; bt = ot; }  // ties: lowest t
    }
    if (lane == 0) {
        pos_row[cell] = y0 + (bt >> 4);
        pos_col[cell] = x0 + (bt & 15);
    }
}

// ---------------- per-sample prep for det1 samples --------------------------------------
// NOTE reference index swap: H-index = pos_col, W-index = pos_row (y1=cols, x1=rows).
// Emits the des1 descriptor as split-bf16 (hi/lo) rows for the MFMA GEMM.
__global__ __launch_bounds__(64) void prep1_kernel(const float* __restrict__ des1,
                                                   const float* __restrict__ des2,
                                                   const float* __restrict__ qlt1,
                                                   const float* __restrict__ qlt2,
                                                   const float* __restrict__ aflow,
                                                   const int* __restrict__ pos_row,
                                                   const int* __restrict__ pos_col,
                                                   int* __restrict__ xy2x_out,
                                                   int* __restrict__ xy2y_out,
                                                   unsigned short* __restrict__ Ahi,
                                                   unsigned short* __restrict__ Alo,
                                                   float* __restrict__ out_scores,
                                                   float* __restrict__ out_mask,
                                                   float* __restrict__ out_qlt) {
    int n = blockIdx.x;                      // grid = NSP_ (3648), rows >= NS_ are zero pad
    int lane = threadIdx.x;                  // 64 lanes, each owns d and d+64
    size_t o = (size_t)n * D_ + lane;
    if (n >= NS_) {
        Ahi[o] = 0; Ahi[o + 64] = 0;
        Alo[o] = 0; Alo[o + 64] = 0;
        return;
    }
    int b = n / NCELL_;
    int row = pos_row[n], col = pos_col[n];
    int d0 = lane;

    const float* p1 = des1 + ((b * D_ + d0) * H_ + col) * W_ + row;
    float a0 = p1[0];
    float a1 = p1[64 * H_ * W_];

    // split-bf16: a = hi + lo + O(2^-17 * a); subtraction a - bf2f(hi) is exact in f32
    unsigned short h0 = f2bf(a0), h1 = f2bf(a1);
    Ahi[o] = h0;            Ahi[o + 64] = h1;
    Alo[o] = f2bf(a0 - bf2f(h0));
    Alo[o + 64] = f2bf(a1 - bf2f(h1));

    float fx = aflow[((b * 2 + 0) * H_ + col) * W_ + row];
    float fy = aflow[((b * 2 + 1) * H_ + col) * W_ + row];
    int xx = (int)(fx + 0.5f);               // trunc toward zero, matches astype(int32)
    int yy = (int)(fy + 0.5f);

    // preload all 13 neighbors (both halves) before reducing -> 26 loads in flight
    float v0s[NK_], v1s[NK_];
#pragma unroll
    for (int k = 0; k < NK_; k++) {
        int X = min(max(xx + c_OI[k], 0), W_ - 1);
        int Y = min(max(yy + c_OJ[k], 0), H_ - 1);
        const float* p2 = des2 + ((b * D_ + d0) * H_ + Y) * W_ + X;
        v0s[k] = p2[0];
        v1s[k] = p2[64 * H_ * W_];
    }

    // exact f32 dot products -> argmax selection is bit-identical to the old kernel
    float bestv = -1e30f; int bestk = 0;
#pragma unroll
    for (int k = 0; k < NK_; k++) {
        float p = a0 * v0s[k] + a1 * v1s[k];
        for (int s = 32; s > 0; s >>= 1) p += __shfl_xor(p, s, 64);
        if (p > bestv) { bestv = p; bestk = k; }   // strict > = first occurrence
    }

    if (lane == 0) {
        out_scores[(size_t)n * SC_] = bestv;       // pscores (exact f32)
        bool m = (xx >= 0) && (yy >= 0) && (xx < W_) && (yy < H_);
        out_mask[n] = m ? 1.0f : 0.0f;
        int sx = min(max(xx + c_OI[bestk], 0), W_ - 1);
        int sy = min(max(yy + c_OJ[bestk], 0), H_ - 1);
        float q1 = qlt1[(b * H_ + col) * W_ + row];
        float q2 = qlt2[(b * H_ + sy) * W_ + sx];
        out_qlt[n] = (q1 + q2) * 0.5f;
        xy2x_out[n] = xx;
        xy2y_out[n] = yy;
    }
}

// ---------------- gather distr (det2 samples) as split-bf16 -----------------------------
__global__ __launch_bounds__(64) void prep2_kernel(const float* __restrict__ des2,
                                                   const int* __restrict__ pos_row2,
                                                   const int* __restrict__ pos_col2,
                                                   unsigned short* __restrict__ Bhi,
                                                   unsigned short* __restrict__ Blo) {
    int m = blockIdx.x;                      // grid = NSP_, rows >= NS_ are zero pad
    int lane = threadIdx.x;
    size_t o = (size_t)m * D_ + lane;
    if (m >= NS_) {
        Bhi[o] = 0; Bhi[o + 64] = 0;
        Blo[o] = 0; Blo[o + 64] = 0;
        return;
    }
    int b = m / NCELL_;
    int row = pos_row2[m], col = pos_col2[m];
    const float* p = des2 + ((b * D_ + lane) * H_ + col) * W_ + row;
    float a0 = p[0];
    float a1 = p[64 * H_ * W_];
    unsigned short h0 = f2bf(a0), h1 = f2bf(a1);
    Bhi[o] = h0;            Bhi[o + 64] = h1;
    Blo[o] = f2bf(a0 - bf2f(h0));
    Blo[o + 64] = f2bf(a1 - bf2f(h1));
}

// ---------------- labels: streaming zero fill, then scatter the ones --------------------
__global__ void zero_labels(float4* __restrict__ labels4) {
    const long long N4 = (long long)NS_ * SC_ / 4;   // 3,240,900
    long long i = (long long)blockIdx.x * blockDim.x + threadIdx.x;
    long long stride = (long long)gridDim.x * blockDim.x;
    float4 z = make_float4(0.f, 0.f, 0.f, 0.f);
    for (; i < N4; i += stride) labels4[i] = z;
}
__global__ void ones_labels(float* __restrict__ labels) {
    int n = blockIdx.x * blockDim.x + threadIdx.x;
    if (n < NS_) labels[(size_t)n * SC_] = 1.0f;
}

// ---------------- dscores GEMM: split-bf16 MFMA, direct-from-L2 fragments ---------------
// dscores = A * B^T, A/B stored row-major [n][128] as bf16 hi/lo.
// C ~= Ah*Bh + Ah*Bl + Al*Bh  (dropped Al*Bl term ~2^-16 relative; dot error ~3e-4)
// 64x64 tile per block, 4 waves in 2x2, each wave 32x32 = 2x2 fragments of 16x16x32.
__global__ __launch_bounds__(256) void gemm_mfma_kernel(const unsigned short* __restrict__ Ahi,
                                                        const unsigned short* __restrict__ Alo,
                                                        const unsigned short* __restrict__ Bhi,
                                                        const unsigned short* __restrict__ Blo,
                                                        const int* __restrict__ xy2x,
                                                        const int* __restrict__ xy2y,
                                                        const int* __restrict__ pos_row2,
                                                        const int* __restrict__ pos_col2,
                                                        float* __restrict__ out_scores) {
    int t    = threadIdx.x;
    int wave = t >> 6;
    int lane = t & 63;
    int wr = wave >> 1, wc = wave & 1;
    int n0 = blockIdx.y * 64 + wr * 32;
    int m0 = blockIdx.x * 64 + wc * 32;
    int c = lane & 15;            // A: M-row / B: N-col / C: N-col  (m89-verified layout)
    int g = lane >> 4;            // k-group of 8 contiguous bf16

    f32x4 acc[2][2] = {};

#pragma unroll
    for (int ks = 0; ks < 4; ks++) {
        int ko = ks * 32 + g * 8;
        short8v ah[2], al[2], bh[2], bl[2];
#pragma unroll
        for (int f = 0; f < 2; f++) {
            size_t ai = (size_t)(n0 + f * 16 + c) * D_ + ko;
            size_t bi = (size_t)(m0 + f * 16 + c) * D_ + ko;
            ah[f] = *(const short8v*)(Ahi + ai);
            al[f] = *(const short8v*)(Alo + ai);
            bh[f] = *(const short8v*)(Bhi + bi);
            bl[f] = *(const short8v*)(Blo + bi);
        }
#pragma unroll
        for (int i = 0; i < 2; i++)
#pragma unroll
            for (int j = 0; j < 2; j++) {
                acc[i][j] = __builtin_amdgcn_mfma_f32_16x16x32_bf16(ah[i], bh[j], acc[i][j], 0, 0, 0);
                acc[i][j] = __builtin_amdgcn_mfma_f32_16x16x32_bf16(ah[i], bl[j], acc[i][j], 0, 0, 0);
                acc[i][j] = __builtin_amdgcn_mfma_f32_16x16x32_bf16(al[i], bh[j], acc[i][j], 0, 0, 0);
            }
    }

    // epilogue: dis2 mask, store to scores[:, 1:]
    int mcol[2], rm[2], cm[2], bm[2];
#pragma unroll
    for (int j = 0; j < 2; j++) {
        mcol[j] = m0 + j * 16 + c;
        if (mcol[j] < NS_) {
            rm[j] = pos_row2[mcol[j]]; cm[j] = pos_col2[mcol[j]]; bm[j] = mcol[j] / NCELL_;
        }
    }
#pragma unroll
    for (int i = 0; i < 2; i++) {
#pragma unroll
        for (int r = 0; r < 4; r++) {
            int n = n0 + i * 16 + g * 4 + r;          // C row = (lane>>4)*4 + reg
            if (n >= NS_) continue;
            int xr = xy2x[n], yr = xy2y[n], br = n / NCELL_;
#pragma unroll
            for (int j = 0; j < 2; j++) {
                if (mcol[j] >= NS_) continue;
                // dis2 = (rows2 - x)^2 + (cols2 - y)^2 (+4 if batch differs); UNCLAMPED xy2
                int dx = rm[j] - xr;
                int dy = cm[j] - yr;
                int dis2 = dx * dx + dy * dy + (bm[j] != br ? 4 : 0);
                float v = acc[i][j][r];
                out_scores[(size_t)n * SC_ + 1 + mcol[j]] = (dis2 < 4) ? 0.0f : v;
            }
        }
    }
}

extern "C" void kernel_launch(void* const* d_in, const int* in_sizes, int n_in,
                              void* d_out, int out_size, void* d_ws, size_t ws_size,
                              hipStream_t stream) {
    const float* des1  = (const float*)d_in[0];
    const float* det1  = (const float*)d_in[1];
    const float* qlt1  = (const float*)d_in[2];
    const float* des2  = (const float*)d_in[3];
    const float* det2  = (const float*)d_in[4];
    const float* qlt2  = (const float*)d_in[5];
    const float* aflow = (const float*)d_in[6];

    float* out = (float*)d_out;
    float* out_scores = out;                                        // (3600, 3601)
    float* out_labels = out + (size_t)NS_ * SC_;                    // (3600, 3601)
    float* out_mask   = out + 2 * (size_t)NS_ * SC_;                // (4, 900)
    float* out_qlt    = out + 2 * (size_t)NS_ * SC_ + NS_;          // (3600, 1)

    char* ws = (char*)d_ws;
    int* pos_row = (int*)(ws);                          // [7200] det1 then det2
    int* pos_col = (int*)(ws + 28800);                  // [7200]
    int* xy2x    = (int*)(ws + 57600);                  // [3600]
    int* xy2y    = (int*)(ws + 72000);                  // [3600]
    unsigned short* Ahi = (unsigned short*)(ws +   86400);   // [3648*128] bf16
    unsigned short* Alo = (unsigned short*)(ws + 1020288);
    unsigned short* Bhi = (unsigned short*)(ws + 1954176);
    unsigned short* Blo = (unsigned short*)(ws + 2888064);   // end: 3,821,952 B

    hipLaunchKernelGGL(sample_kernel, dim3(2 * NS_ / 4), dim3(256), 0, stream,
                       det1, det2, pos_row, pos_col);
    hipLaunchKernelGGL(prep1_kernel, dim3(NSP_), dim3(64), 0, stream,
                       des1, des2, qlt1, qlt2, aflow, pos_row, pos_col,
                       xy2x, xy2y, Ahi, Alo, out_scores, out_mask, out_qlt);
    hipLaunchKernelGGL(prep2_kernel, dim3(NSP_), dim3(64), 0, stream,
                       des2, pos_row + NS_, pos_col + NS_, Bhi, Blo);
    hipLaunchKernelGGL(zero_labels, dim3(2048), dim3(256), 0, stream,
                       (float4*)out_labels);
    hipLaunchKernelGGL(ones_labels, dim3((NS_ + 255) / 256), dim3(256), 0, stream,
                       out_labels);
    hipLaunchKernelGGL(gemm_mfma_kernel, dim3(NSP_ / 64, NSP_ / 64), dim3(256), 0, stream,
                       Ahi, Alo, Bhi, Blo, xy2x, xy2y,
                       pos_row + NS_, pos_col + NS_, out_scores);
}